// Round 7
// baseline (308.322 us; speedup 1.0000x reference)
//
#include <hip/hip_runtime.h>

typedef __bf16 bf16_t;
typedef __bf16 bf16x8 __attribute__((ext_vector_type(8)));
typedef float f32x4 __attribute__((ext_vector_type(4)));
typedef unsigned short u16;
typedef unsigned short u16x4 __attribute__((ext_vector_type(4)));
typedef unsigned int u32;

#define B_ 4
#define N_ 64
#define P_ 256
#define C_ 384
#define H_ 6
#define D_ 64
#define M_TOTAL 65536
#define NQKV 1152
#define KSTEPS 12                     // 384/32
#define NBLK (H_*B_*N_)               // 1536 = 8 XCDs * 192
// 20 frags per (h,ks): per col-group cg: [6 hi: Q0 Q1 K0 K1 V0 V1][4 lo: Q0 Q1 K0 K1]
#define WKS_U16 10240                 // 20KB
#define WKS_BYTES 20480
// LDS map (u16 offsets):
//   Kh 0..16384  Kl 16384..32768  Vt 32768..49152
//   stage0 49152..59392, stage1 59392..69632        (phase 1)
//   Qx (shared Q exchange) 49152..65536 (32KB)      (after phase 1)
//   Pb = 49152 + wid*640  (20KB)                    (phase 3)
#define FUSED_LDS 139264
#define PB_STRIDE 40
#define SB() __builtin_amdgcn_sched_barrier(0)

#define GLOAD_LDS16(g, l) __builtin_amdgcn_global_load_lds( \
    (const __attribute__((address_space(1))) void*)(g), \
    (__attribute__((address_space(3))) void*)(l), 16, 0, 0)

__device__ __forceinline__ u16 f2b(float f){ return __builtin_bit_cast(u16, (bf16_t)f); }
__device__ __forceinline__ f32x4 mfma(bf16x8 a, bf16x8 b, f32x4 c){
    return __builtin_amdgcn_mfma_f32_16x16x32_bf16(a, b, c, 0, 0, 0);
}

// ---------------------------------------------------------------------------
// prep: (a) packed per-(h,ks) 20KB weight blocks, col-group-major:
//           fi = cg*10 + f;  f<6: hi frag j=f of [Q(2cg) Q(2cg+1) K(2cg) K(2cg+1) V(2cg) V(2cg+1)]
//                            f>=6: lo frag j=f-6 of [Q Q K K]
//       (b) w_proj^T bf16
// ---------------------------------------------------------------------------
__global__ __launch_bounds__(256) void prep_w(
    const float* __restrict__ wqkv, const float* __restrict__ wproj,
    u16* __restrict__ Wpk, u16* __restrict__ wPt)
{
    int i = blockIdx.x * 256 + threadIdx.x;
    const int NSLOT = H_ * KSTEPS * 20 * 64;   // 92160
    if (i < NSLOT) {
        int lane = i & 63;
        int frag = i >> 6;
        int fi = frag % 20;
        int ks = (frag / 20) % KSTEPS;
        int h  = frag / (20 * KSTEPS);
        int cg = fi / 10;
        int f  = fi % 10;
        int isLo = (f >= 6);
        int j  = isLo ? f - 6 : f;                 // 0..5 (hi) / 0..3 (lo)
        int part = j >> 1;                         // 0=Q 1=K 2=V
        int jj   = j & 1;
        int col  = part * C_ + h * 64 + (cg * 2 + jj) * 16 + (lane & 15);
        int k0   = ks * 32 + (lane >> 4) * 8;
        #pragma unroll
        for (int e = 0; e < 8; ++e) {
            float w = wqkv[(size_t)(k0 + e) * NQKV + col];
            bf16_t hi = (bf16_t)w;
            Wpk[(size_t)i * 8 + e] = isLo ? f2b(w - (float)hi)
                                          : __builtin_bit_cast(u16, hi);
        }
    }
    int j = i - NSLOT;
    if (j >= 0 && j < C_ * C_) {
        int k = j / C_, n = j % C_;
        wPt[(size_t)n * C_ + k] = f2b(wproj[j]);
    }
}

// ---------------------------------------------------------------------------
// fused per-(h, b*n) kernel: 1024 threads = 16 waves.
// Phase 1 (QKV GEMM): wave (rg,cg) owns rows rg*32 x columns half cg ->
//   10 LDS B-reads per 28 MFMAs (2x fewer LDS reads than row-only split).
// Phase 2/3: wave owns 16 q-rows; Q re-distributed via shared LDS exchange.
// ---------------------------------------------------------------------------
__global__ __launch_bounds__(1024, 4) void fused_attn(
    const float* __restrict__ x, const u16* __restrict__ Wpk,
    u16* __restrict__ attn)
{
    extern __shared__ u16 sm[];
    u16* Kh = sm;
    u16* Kl = sm + 16384;
    u16* Vt = sm + 32768;
    u16* Qx = sm + 49152;      // 32KB shared Q exchange (stage region, dead after ph1)

    const int tid  = threadIdx.x;
    const int lane = tid & 63, wid = tid >> 6;
    const int g = lane >> 4, r16 = lane & 15;

    // XCD-chunk swizzle (bijective: 1536 = 8 * 192)
    const int p = blockIdx.x;
    const int logical = (p & 7) * (NBLK / 8) + (p >> 3);
    const int h  = logical % H_;
    const int bn = logical / H_;
    const size_t row0 = (size_t)bn * P_;

    const int rg = wid >> 1;          // phase-1 row group (32 rows)
    const int cg = wid & 1;           // phase-1 column half
    const int m0w1 = rg * 32;

    // ---------------- phase 1 ----------------------------------------------
    f32x4 acc[2][6];
    #pragma unroll
    for (int mf = 0; mf < 2; ++mf)
        #pragma unroll
        for (int j = 0; j < 6; ++j) acc[mf][j] = f32x4{0.f,0.f,0.f,0.f};

    const float* xr0 = x + (row0 + m0w1 + r16) * C_;
    const float* xr1 = xr0 + 16 * C_;
    const char* wbase = (const char*)Wpk + (size_t)h * (KSTEPS * WKS_BYTES);

#define STAGE(ks_, par_) do { \
    const char* _gp = wbase + (size_t)(ks_) * WKS_BYTES; \
    char* _lp = (char*)(sm + 49152 + (par_) * WKS_U16); \
    GLOAD_LDS16(_gp + tid * 16, _lp + tid * 16); \
    if (tid < 256) GLOAD_LDS16(_gp + 16384 + tid * 16, _lp + 16384 + tid * 16); \
} while (0)

    STAGE(0, 0);
    __syncthreads();

    #pragma unroll
    for (int ks = 0; ks < KSTEPS; ++ks) {
        const int par = ks & 1, nxt = par ^ 1;
        if (ks < KSTEPS - 1) STAGE(ks + 1, nxt);

        // A: load + split 2 row-fragments (this wave's 32 rows)
        f32x4 xa0 = *(const f32x4*)(xr0 + ks * 32 + 8 * g);
        f32x4 xa1 = *(const f32x4*)(xr0 + ks * 32 + 8 * g + 4);
        f32x4 xb0 = *(const f32x4*)(xr1 + ks * 32 + 8 * g);
        f32x4 xb1 = *(const f32x4*)(xr1 + ks * 32 + 8 * g + 4);
        bf16x8 ah[2], al[2];
        #pragma unroll
        for (int e = 0; e < 4; ++e) {
            bf16_t h0 = (bf16_t)xa0[e], h1 = (bf16_t)xa1[e];
            ah[0][e]   = h0; al[0][e]   = (bf16_t)(xa0[e] - (float)h0);
            ah[0][4+e] = h1; al[0][4+e] = (bf16_t)(xa1[e] - (float)h1);
            bf16_t h2 = (bf16_t)xb0[e], h3 = (bf16_t)xb1[e];
            ah[1][e]   = h2; al[1][e]   = (bf16_t)(xb0[e] - (float)h2);
            ah[1][4+e] = h3; al[1][4+e] = (bf16_t)(xb1[e] - (float)h3);
        }

        const u16* cgb = sm + 49152 + par * WKS_U16 + cg * 5120;
        #pragma unroll
        for (int j = 0; j < 4; ++j) {      // Q,Q,K,K: split 3x
            bf16x8 bh = *(const bf16x8*)&cgb[j * 512 + lane * 8];
            bf16x8 bl = *(const bf16x8*)&cgb[(6 + j) * 512 + lane * 8];
            #pragma unroll
            for (int mf = 0; mf < 2; ++mf) {
                acc[mf][j] = mfma(ah[mf], bh, acc[mf][j]);
                acc[mf][j] = mfma(ah[mf], bl, acc[mf][j]);
                acc[mf][j] = mfma(al[mf], bh, acc[mf][j]);
            }
        }
        #pragma unroll
        for (int j = 4; j < 6; ++j) {      // V,V: plain
            bf16x8 bh = *(const bf16x8*)&cgb[j * 512 + lane * 8];
            #pragma unroll
            for (int mf = 0; mf < 2; ++mf)
                acc[mf][j] = mfma(ah[mf], bh, acc[mf][j]);
        }
        __syncthreads();   // stage(ks+1) drained + all waves done with stg[par]
    }

    // ---- epilogue: K -> Kh/Kl, V -> Vt, Q(hi) -> Qx (all swizzled) --------
    #pragma unroll
    for (int mf = 0; mf < 2; ++mf)
    #pragma unroll
    for (int jj = 0; jj < 2; ++jj)
    #pragma unroll
    for (int rr = 0; rr < 4; ++rr) {
        int q = m0w1 + mf * 16 + 4 * g + rr;
        int d = (cg * 2 + jj) * 16 + r16;
        // K (j = 2+jj)
        int ek = q * 64 + (((d >> 3) ^ (q & 7)) << 3) + (d & 7);
        float kv = acc[mf][2 + jj][rr];
        bf16_t khi = (bf16_t)kv;
        Kh[ek] = __builtin_bit_cast(u16, khi);
        Kl[ek] = f2b(kv - (float)khi);
        // V (j = 4+jj)
        Vt[d * 256 + (((q >> 3) ^ (d & 7)) << 3) + (q & 7)] = f2b(acc[mf][4 + jj][rr]);
        // Q hi (j = jj)
        Qx[ek] = f2b(acc[mf][jj][rr]);
    }
    __syncthreads();                       // Qx(hi), Kh/Kl/Vt visible

    const int m0w = wid * 16;              // phase-2/3 row ownership
    bf16x8 aqh[2], aql[2];
    #pragma unroll
    for (int k2 = 0; k2 < 2; ++k2) {
        int q = m0w + r16;
        aqh[k2] = *(const bf16x8*)&Qx[q * 64 + (((k2 * 4 + g) ^ (q & 7)) << 3)];
    }
    __syncthreads();                       // all hi reads done
    #pragma unroll
    for (int mf = 0; mf < 2; ++mf)
    #pragma unroll
    for (int jj = 0; jj < 2; ++jj)
    #pragma unroll
    for (int rr = 0; rr < 4; ++rr) {
        int q = m0w1 + mf * 16 + 4 * g + rr;
        int d = (cg * 2 + jj) * 16 + r16;
        float v = acc[mf][jj][rr];
        bf16_t hi = (bf16_t)v;
        Qx[q * 64 + (((d >> 3) ^ (q & 7)) << 3) + (d & 7)] = f2b(v - (float)hi);
    }
    __syncthreads();                       // Qx(lo) visible
    #pragma unroll
    for (int k2 = 0; k2 < 2; ++k2) {
        int q = m0w + r16;
        aql[k2] = *(const bf16x8*)&Qx[q * 64 + (((k2 * 4 + g) ^ (q & 7)) << 3)];
    }
    __syncthreads();                       // all lo reads done (Qx region free)

    // ---------------- phase 2: S = Q K^T (split, 3 MFMA), prefetch 1 nf ----
    f32x4 S[16];
    #pragma unroll
    for (int nf = 0; nf < 16; ++nf) S[nf] = f32x4{0.f,0.f,0.f,0.f};

    bf16x8 khv[2][2], klv[2][2];
    {
        int q = r16;
        #pragma unroll
        for (int k2 = 0; k2 < 2; ++k2) {
            int e = q * 64 + (((k2 * 4 + g) ^ (q & 7)) << 3);
            khv[0][k2] = *(const bf16x8*)&Kh[e];
            klv[0][k2] = *(const bf16x8*)&Kl[e];
        }
    }
    #pragma unroll
    for (int nf = 0; nf < 16; ++nf) {
        const int par = nf & 1, nxt = par ^ 1;
        if (nf < 15) {
            int q = (nf + 1) * 16 + r16;
            #pragma unroll
            for (int k2 = 0; k2 < 2; ++k2) {
                int e = q * 64 + (((k2 * 4 + g) ^ (q & 7)) << 3);
                khv[nxt][k2] = *(const bf16x8*)&Kh[e];
                klv[nxt][k2] = *(const bf16x8*)&Kl[e];
            }
        }
        SB();
        __builtin_amdgcn_s_setprio(1);
        #pragma unroll
        for (int k2 = 0; k2 < 2; ++k2) {
            S[nf] = mfma(aqh[k2], khv[par][k2], S[nf]);
            S[nf] = mfma(aqh[k2], klv[par][k2], S[nf]);
            S[nf] = mfma(aql[k2], khv[par][k2], S[nf]);
        }
        __builtin_amdgcn_s_setprio(0);
        SB();
    }

    // ---------------- softmax (rows lane-spread over 16 lanes) -------------
    {
        float mrow[4] = {-1e30f,-1e30f,-1e30f,-1e30f};
        #pragma unroll
        for (int nf = 0; nf < 16; ++nf)
            #pragma unroll
            for (int rr = 0; rr < 4; ++rr) mrow[rr] = fmaxf(mrow[rr], S[nf][rr]);
        #pragma unroll
        for (int mask = 1; mask < 16; mask <<= 1)
            #pragma unroll
            for (int rr = 0; rr < 4; ++rr) mrow[rr] = fmaxf(mrow[rr], __shfl_xor(mrow[rr], mask, 64));
        float ssum[4] = {0.f,0.f,0.f,0.f};
        #pragma unroll
        for (int nf = 0; nf < 16; ++nf)
            #pragma unroll
            for (int rr = 0; rr < 4; ++rr) {
                float pv = __expf((S[nf][rr] - mrow[rr]) * 64.0f);  // scale = D
                S[nf][rr] = pv;
                ssum[rr] += pv;
            }
        #pragma unroll
        for (int mask = 1; mask < 16; mask <<= 1)
            #pragma unroll
            for (int rr = 0; rr < 4; ++rr) ssum[rr] += __shfl_xor(ssum[rr], mask, 64);
        float inv_[4];
        #pragma unroll
        for (int rr = 0; rr < 4; ++rr) inv_[rr] = 1.0f / ssum[rr];
        #pragma unroll
        for (int nf = 0; nf < 16; ++nf)
            #pragma unroll
            for (int rr = 0; rr < 4; ++rr) S[nf][rr] *= inv_[rr];
    }

    // ---------------- phase 3: O = P V (per-wave bounce, stride 40) --------
    f32x4 O[4];
    #pragma unroll
    for (int f = 0; f < 4; ++f) O[f] = f32x4{0.f,0.f,0.f,0.f};

    u16* pb = sm + 49152 + wid * 640;        // [16][PB_STRIDE]
    #pragma unroll
    for (int t = 0; t < 8; ++t) {
        bf16x8 bv[4];
        #pragma unroll
        for (int f = 0; f < 4; ++f) {
            int d = f * 16 + r16;
            bv[f] = *(const bf16x8*)&Vt[d * 256 + ((((t * 32 + 8 * g) >> 3) ^ (d & 7)) << 3)];
        }
        #pragma unroll
        for (int tt = 0; tt < 2; ++tt) {
            int nf = 2 * t + tt;
            #pragma unroll
            for (int rr = 0; rr < 4; ++rr)
                pb[(4 * g + rr) * PB_STRIDE + tt * 16 + r16] = f2b(S[nf][rr]);
        }
        bf16x8 ap = *(const bf16x8*)&pb[r16 * PB_STRIDE + 8 * g];
        __builtin_amdgcn_s_setprio(1);
        #pragma unroll
        for (int f = 0; f < 4; ++f) O[f] = mfma(ap, bv[f], O[f]);
        __builtin_amdgcn_s_setprio(0);
    }

    #pragma unroll
    for (int f = 0; f < 4; ++f)
    #pragma unroll
    for (int rr = 0; rr < 4; ++rr)
        attn[(row0 + m0w + 4 * g + rr) * C_ + h * 64 + f * 16 + r16] = f2b(O[f][rr]);
}

// ---------------------------------------------------------------------------
// proj: attn(65536x384 bf16) @ w_proj(384x384) + bias -> f32 out.
// ---------------------------------------------------------------------------
__global__ __launch_bounds__(256, 2) void proj_kernel(
    const u16* __restrict__ attn, const u16* __restrict__ wPt,
    const float* __restrict__ bias, float* __restrict__ out)
{
    __shared__ alignas(16) u16 As[128*32];
    __shared__ alignas(16) u16 Bs[128*32];

    const int tid = threadIdx.x;
    const int lane = tid & 63, wid = tid >> 6;
    const int wr = wid >> 1, wc = wid & 1;
    const int g = lane >> 4, r16 = lane & 15;
    const int m0 = blockIdx.x * 128;
    const int n0 = blockIdx.y * 128;

    f32x4 acc[4][4];
    for (int i = 0; i < 4; i++) for (int j = 0; j < 4; j++) acc[i][j] = f32x4{0.f,0.f,0.f,0.f};

    for (int kt = 0; kt < C_; kt += 32) {
        for (int r = 0; r < 4; ++r) {
            int i = tid + 256*r;
            int mm = i >> 3;
            int kk = (i & 7) << 2;
            u16x4 v = *(const u16x4*)&attn[(size_t)(m0+mm)*C_ + kt + kk];
            int e = mm*32 + (((kk>>3) ^ ((mm>>1)&3))<<3) + (kk&7);
            *(u16x4*)&As[e] = v;
        }
        for (int r = 0; r < 4; ++r) {
            int i = tid + 256*r;
            int nn = i >> 3;
            int kk = (i & 7) << 2;
            u16x4 v = *(const u16x4*)&wPt[(size_t)(n0+nn)*C_ + kt + kk];
            int e = nn*32 + (((kk>>3) ^ ((nn>>1)&3))<<3) + (kk&7);
            *(u16x4*)&Bs[e] = v;
        }
        __syncthreads();

        bf16x8 a[4], b[4];
        for (int i = 0; i < 4; i++) {
            int row = wr*64 + i*16 + r16;
            a[i] = *(const bf16x8*)&As[row*32 + ((g ^ ((row>>1)&3))<<3)];
        }
        for (int j = 0; j < 4; j++) {
            int n = wc*64 + j*16 + r16;
            b[j] = *(const bf16x8*)&Bs[n*32 + ((g ^ ((n>>1)&3))<<3)];
        }
        for (int i = 0; i < 4; i++) for (int j = 0; j < 4; j++)
            acc[i][j] = mfma(a[i], b[j], acc[i][j]);
        __syncthreads();
    }

    for (int i = 0; i < 4; i++) for (int j = 0; j < 4; j++) for (int rr = 0; rr < 4; rr++) {
        size_t row = m0 + wr*64 + i*16 + g*4 + rr;
        int col = n0 + wc*64 + j*16 + r16;
        out[row*C_ + col] = acc[i][j][rr] + bias[col];
    }
}

// ---------------------------------------------------------------------------
extern "C" void kernel_launch(void* const* d_in, const int* in_sizes, int n_in,
                              void* d_out, int out_size, void* d_ws, size_t ws_size,
                              hipStream_t stream)
{
    const float* x      = (const float*)d_in[0];
    const float* w_qkv  = (const float*)d_in[1];
    const float* w_proj = (const float*)d_in[2];
    const float* b_proj = (const float*)d_in[3];
    float* out = (float*)d_out;

    u16* ws = (u16*)d_ws;
    u16* attnb = ws;                                  // 65536*384 u16 = 50 MB
    size_t off = (size_t)M_TOTAL * C_;
    u16* Wpk = ws + off; off += (size_t)H_ * KSTEPS * WKS_U16;
    u16* wPt = ws + off; off += (size_t)C_ * C_;

    hipFuncSetAttribute((const void*)fused_attn,
                        hipFuncAttributeMaxDynamicSharedMemorySize, FUSED_LDS);

    int prep_n = H_ * KSTEPS * 20 * 64 + C_ * C_;
    prep_w<<<dim3((prep_n + 255) / 256), 256, 0, stream>>>(w_qkv, w_proj, Wpk, wPt);
    fused_attn<<<dim3(NBLK), 1024, FUSED_LDS, stream>>>(x, Wpk, attnb);
    proj_kernel<<<dim3(M_TOTAL / 128, C_ / 128), 256, 0, stream>>>(attnb, wPt, b_proj, out);
}

// Round 8
// 301.304 us; speedup vs baseline: 1.0233x; 1.0233x over previous
//
#include <hip/hip_runtime.h>

typedef __bf16 bf16_t;
typedef __bf16 bf16x8 __attribute__((ext_vector_type(8)));
typedef float f32x4 __attribute__((ext_vector_type(4)));
typedef unsigned short u16;
typedef unsigned short u16x4 __attribute__((ext_vector_type(4)));
typedef unsigned int u32;

#define B_ 4
#define N_ 64
#define P_ 256
#define C_ 384
#define H_ 6
#define D_ 64
#define M_TOTAL 65536
#define NQKV 1152
#define KSTEPS 12                     // 384/32
#define NBLK (H_*B_*N_)               // 1536 = 8 XCDs * 192
// 20 frags per (h,ks): per col-group cg: [6 hi: Q0 Q1 K0 K1 V0 V1][4 lo: Q0 Q1 K0 K1]
#define WKS_U16 10240                 // 20KB
#define WKS_BYTES 20480
// LDS map (u16 offsets):
//   Kh 0..16384  Kl 16384..32768  Vt 32768..49152
//   stage0 49152..59392, stage1 59392..69632        (phase 1)
//   Qx (shared Q exchange) 49152..65536 (32KB)      (after phase 1)
//   Pb = 49152 + wid*640  (20KB)                    (phase 3)
#define FUSED_LDS 139264
#define PB_STRIDE 40
#define SB() __builtin_amdgcn_sched_barrier(0)

#define GLOAD_LDS16(g, l) __builtin_amdgcn_global_load_lds( \
    (const __attribute__((address_space(1))) void*)(g), \
    (__attribute__((address_space(3))) void*)(l), 16, 0, 0)

__device__ __forceinline__ u16 f2b(float f){ return __builtin_bit_cast(u16, (bf16_t)f); }
__device__ __forceinline__ f32x4 mfma(bf16x8 a, bf16x8 b, f32x4 c){
    return __builtin_amdgcn_mfma_f32_16x16x32_bf16(a, b, c, 0, 0, 0);
}

// ---------------------------------------------------------------------------
// prep: (a) packed per-(h,ks) 20KB weight blocks, col-group-major:
//           fi = cg*10 + f;  f<6: hi frag j=f of [Q(2cg) Q(2cg+1) K(2cg) K(2cg+1) V(2cg) V(2cg+1)]
//                            f>=6: lo frag j=f-6 of [Q Q K K]
//       (b) w_proj^T bf16
// ---------------------------------------------------------------------------
__global__ __launch_bounds__(256) void prep_w(
    const float* __restrict__ wqkv, const float* __restrict__ wproj,
    u16* __restrict__ Wpk, u16* __restrict__ wPt)
{
    int i = blockIdx.x * 256 + threadIdx.x;
    const int NSLOT = H_ * KSTEPS * 20 * 64;   // 92160
    if (i < NSLOT) {
        int lane = i & 63;
        int frag = i >> 6;
        int fi = frag % 20;
        int ks = (frag / 20) % KSTEPS;
        int h  = frag / (20 * KSTEPS);
        int cg = fi / 10;
        int f  = fi % 10;
        int isLo = (f >= 6);
        int j  = isLo ? f - 6 : f;                 // 0..5 (hi) / 0..3 (lo)
        int part = j >> 1;                         // 0=Q 1=K 2=V
        int jj   = j & 1;
        int col  = part * C_ + h * 64 + (cg * 2 + jj) * 16 + (lane & 15);
        int k0   = ks * 32 + (lane >> 4) * 8;
        #pragma unroll
        for (int e = 0; e < 8; ++e) {
            float w = wqkv[(size_t)(k0 + e) * NQKV + col];
            bf16_t hi = (bf16_t)w;
            Wpk[(size_t)i * 8 + e] = isLo ? f2b(w - (float)hi)
                                          : __builtin_bit_cast(u16, hi);
        }
    }
    int j = i - NSLOT;
    if (j >= 0 && j < C_ * C_) {
        int k = j / C_, n = j % C_;
        wPt[(size_t)n * C_ + k] = f2b(wproj[j]);
    }
}

// ---------------------------------------------------------------------------
// fused per-(h, b*n) kernel: 1024 threads = 16 waves.
// Phase 1 (QKV GEMM): wave (rg,cg) owns rows rg*32 x columns half cg ->
//   10 LDS B-reads per 28 MFMAs; x loads ping-pong-prefetched one ks ahead
//   (round-7 removed the prefetch -> exposed L2 latency -> regression).
// Phase 2/3: wave owns 16 q-rows; Q re-distributed via shared LDS exchange.
// ---------------------------------------------------------------------------
__global__ __launch_bounds__(1024, 4) void fused_attn(
    const float* __restrict__ x, const u16* __restrict__ Wpk,
    u16* __restrict__ attn)
{
    extern __shared__ u16 sm[];
    u16* Kh = sm;
    u16* Kl = sm + 16384;
    u16* Vt = sm + 32768;
    u16* Qx = sm + 49152;      // 32KB shared Q exchange (stage region, dead after ph1)

    const int tid  = threadIdx.x;
    const int lane = tid & 63, wid = tid >> 6;
    const int g = lane >> 4, r16 = lane & 15;

    // XCD-chunk swizzle (bijective: 1536 = 8 * 192)
    const int p = blockIdx.x;
    const int logical = (p & 7) * (NBLK / 8) + (p >> 3);
    const int h  = logical % H_;
    const int bn = logical / H_;
    const size_t row0 = (size_t)bn * P_;

    const int rg = wid >> 1;          // phase-1 row group (32 rows)
    const int cg = wid & 1;           // phase-1 column half
    const int m0w1 = rg * 32;

    // ---------------- phase 1 ----------------------------------------------
    f32x4 acc[2][6];
    #pragma unroll
    for (int mf = 0; mf < 2; ++mf)
        #pragma unroll
        for (int j = 0; j < 6; ++j) acc[mf][j] = f32x4{0.f,0.f,0.f,0.f};

    const float* xr0 = x + (row0 + m0w1 + r16) * C_;
    const float* xr1 = xr0 + 16 * C_;
    const char* wbase = (const char*)Wpk + (size_t)h * (KSTEPS * WKS_BYTES);

#define STAGE(ks_, par_) do { \
    const char* _gp = wbase + (size_t)(ks_) * WKS_BYTES; \
    char* _lp = (char*)(sm + 49152 + (par_) * WKS_U16); \
    GLOAD_LDS16(_gp + tid * 16, _lp + tid * 16); \
    if (tid < 256) GLOAD_LDS16(_gp + 16384 + tid * 16, _lp + 16384 + tid * 16); \
} while (0)

    f32x4 xr[2][4];            // ping-pong x prefetch: 2 row frags x 8 floats
#define XLOAD(ks_, par_) do { \
    const float* _xp0 = xr0 + (ks_) * 32 + 8 * g; \
    const float* _xp1 = xr1 + (ks_) * 32 + 8 * g; \
    xr[par_][0] = *(const f32x4*)_xp0; xr[par_][1] = *(const f32x4*)(_xp0 + 4); \
    xr[par_][2] = *(const f32x4*)_xp1; xr[par_][3] = *(const f32x4*)(_xp1 + 4); \
} while (0)

    bf16x8 ah[2], al[2];
#define SPLIT_A(par_) do { \
    _Pragma("unroll") \
    for (int e = 0; e < 4; ++e) { \
        bf16_t h0 = (bf16_t)xr[par_][0][e], h1 = (bf16_t)xr[par_][1][e]; \
        ah[0][e]   = h0; al[0][e]   = (bf16_t)(xr[par_][0][e] - (float)h0); \
        ah[0][4+e] = h1; al[0][4+e] = (bf16_t)(xr[par_][1][e] - (float)h1); \
        bf16_t h2 = (bf16_t)xr[par_][2][e], h3 = (bf16_t)xr[par_][3][e]; \
        ah[1][e]   = h2; al[1][e]   = (bf16_t)(xr[par_][2][e] - (float)h2); \
        ah[1][4+e] = h3; al[1][4+e] = (bf16_t)(xr[par_][3][e] - (float)h3); \
    } } while (0)

    STAGE(0, 0);
    XLOAD(0, 0);
    __syncthreads();

    #pragma unroll
    for (int ks = 0; ks < KSTEPS; ++ks) {
        const int par = ks & 1, nxt = par ^ 1;
        if (ks < KSTEPS - 1) {
            STAGE(ks + 1, nxt);       // async global->LDS, drains at end barrier
            XLOAD(ks + 1, nxt);       // x prefetch one ks ahead
        }
        SPLIT_A(par);

        const u16* cgb = sm + 49152 + par * WKS_U16 + cg * 5120;
        #pragma unroll
        for (int j = 0; j < 4; ++j) {      // Q,Q,K,K: split 3x
            bf16x8 bh = *(const bf16x8*)&cgb[j * 512 + lane * 8];
            bf16x8 bl = *(const bf16x8*)&cgb[(6 + j) * 512 + lane * 8];
            #pragma unroll
            for (int mf = 0; mf < 2; ++mf) {
                acc[mf][j] = mfma(ah[mf], bh, acc[mf][j]);
                acc[mf][j] = mfma(ah[mf], bl, acc[mf][j]);
                acc[mf][j] = mfma(al[mf], bh, acc[mf][j]);
            }
        }
        #pragma unroll
        for (int j = 4; j < 6; ++j) {      // V,V: plain
            bf16x8 bh = *(const bf16x8*)&cgb[j * 512 + lane * 8];
            #pragma unroll
            for (int mf = 0; mf < 2; ++mf)
                acc[mf][j] = mfma(ah[mf], bh, acc[mf][j]);
        }
        __syncthreads();   // stage(ks+1) drained + all waves done with stg[par]
    }

    // ---- epilogue: K -> Kh/Kl, V -> Vt (b64-packed), Q(hi) -> Qx ----------
    #pragma unroll
    for (int mf = 0; mf < 2; ++mf)
    #pragma unroll
    for (int jj = 0; jj < 2; ++jj) {
        const int d = (cg * 2 + jj) * 16 + r16;
        const int q0 = m0w1 + mf * 16 + 4 * g;
        // V: 4 consecutive q land in contiguous u16s of the transposed row
        u16x4 vv;
        #pragma unroll
        for (int rr = 0; rr < 4; ++rr) vv[rr] = f2b(acc[mf][4 + jj][rr]);
        *(u16x4*)&Vt[d * 256 + (((q0 >> 3) ^ (d & 7)) << 3) + (q0 & 7)] = vv;
        #pragma unroll
        for (int rr = 0; rr < 4; ++rr) {
            int q = q0 + rr;
            int ek = q * 64 + (((d >> 3) ^ (q & 7)) << 3) + (d & 7);
            float kv = acc[mf][2 + jj][rr];
            bf16_t khi = (bf16_t)kv;
            Kh[ek] = __builtin_bit_cast(u16, khi);
            Kl[ek] = f2b(kv - (float)khi);
            Qx[ek] = f2b(acc[mf][jj][rr]);
        }
    }
    __syncthreads();                       // Qx(hi), Kh/Kl/Vt visible

    const int m0w = wid * 16;              // phase-2/3 row ownership
    bf16x8 aqh[2], aql[2];
    #pragma unroll
    for (int k2 = 0; k2 < 2; ++k2) {
        int q = m0w + r16;
        aqh[k2] = *(const bf16x8*)&Qx[q * 64 + (((k2 * 4 + g) ^ (q & 7)) << 3)];
    }
    __syncthreads();                       // all hi reads done
    #pragma unroll
    for (int mf = 0; mf < 2; ++mf)
    #pragma unroll
    for (int jj = 0; jj < 2; ++jj)
    #pragma unroll
    for (int rr = 0; rr < 4; ++rr) {
        int q = m0w1 + mf * 16 + 4 * g + rr;
        int d = (cg * 2 + jj) * 16 + r16;
        float v = acc[mf][jj][rr];
        bf16_t hi = (bf16_t)v;
        Qx[q * 64 + (((d >> 3) ^ (q & 7)) << 3) + (d & 7)] = f2b(v - (float)hi);
    }
    __syncthreads();                       // Qx(lo) visible
    #pragma unroll
    for (int k2 = 0; k2 < 2; ++k2) {
        int q = m0w + r16;
        aql[k2] = *(const bf16x8*)&Qx[q * 64 + (((k2 * 4 + g) ^ (q & 7)) << 3)];
    }
    __syncthreads();                       // all lo reads done (Qx region free)

    // ---------------- phase 2: S = Q K^T (split, 3 MFMA), prefetch 1 nf ----
    f32x4 S[16];
    #pragma unroll
    for (int nf = 0; nf < 16; ++nf) S[nf] = f32x4{0.f,0.f,0.f,0.f};

    bf16x8 khv[2][2], klv[2][2];
    {
        int q = r16;
        #pragma unroll
        for (int k2 = 0; k2 < 2; ++k2) {
            int e = q * 64 + (((k2 * 4 + g) ^ (q & 7)) << 3);
            khv[0][k2] = *(const bf16x8*)&Kh[e];
            klv[0][k2] = *(const bf16x8*)&Kl[e];
        }
    }
    #pragma unroll
    for (int nf = 0; nf < 16; ++nf) {
        const int par = nf & 1, nxt = par ^ 1;
        if (nf < 15) {
            int q = (nf + 1) * 16 + r16;
            #pragma unroll
            for (int k2 = 0; k2 < 2; ++k2) {
                int e = q * 64 + (((k2 * 4 + g) ^ (q & 7)) << 3);
                khv[nxt][k2] = *(const bf16x8*)&Kh[e];
                klv[nxt][k2] = *(const bf16x8*)&Kl[e];
            }
        }
        SB();
        __builtin_amdgcn_s_setprio(1);
        #pragma unroll
        for (int k2 = 0; k2 < 2; ++k2) {
            S[nf] = mfma(aqh[k2], khv[par][k2], S[nf]);
            S[nf] = mfma(aqh[k2], klv[par][k2], S[nf]);
            S[nf] = mfma(aql[k2], khv[par][k2], S[nf]);
        }
        __builtin_amdgcn_s_setprio(0);
        SB();
    }

    // ---------------- softmax (rows lane-spread over 16 lanes) -------------
    {
        float mrow[4] = {-1e30f,-1e30f,-1e30f,-1e30f};
        #pragma unroll
        for (int nf = 0; nf < 16; ++nf)
            #pragma unroll
            for (int rr = 0; rr < 4; ++rr) mrow[rr] = fmaxf(mrow[rr], S[nf][rr]);
        #pragma unroll
        for (int mask = 1; mask < 16; mask <<= 1)
            #pragma unroll
            for (int rr = 0; rr < 4; ++rr) mrow[rr] = fmaxf(mrow[rr], __shfl_xor(mrow[rr], mask, 64));
        float ssum[4] = {0.f,0.f,0.f,0.f};
        #pragma unroll
        for (int nf = 0; nf < 16; ++nf)
            #pragma unroll
            for (int rr = 0; rr < 4; ++rr) {
                float pv = __expf((S[nf][rr] - mrow[rr]) * 64.0f);  // scale = D
                S[nf][rr] = pv;
                ssum[rr] += pv;
            }
        #pragma unroll
        for (int mask = 1; mask < 16; mask <<= 1)
            #pragma unroll
            for (int rr = 0; rr < 4; ++rr) ssum[rr] += __shfl_xor(ssum[rr], mask, 64);
        float inv_[4];
        #pragma unroll
        for (int rr = 0; rr < 4; ++rr) inv_[rr] = 1.0f / ssum[rr];
        #pragma unroll
        for (int nf = 0; nf < 16; ++nf)
            #pragma unroll
            for (int rr = 0; rr < 4; ++rr) S[nf][rr] *= inv_[rr];
    }

    // ---------------- phase 3: O = P V (per-wave bounce, stride 40) --------
    f32x4 O[4];
    #pragma unroll
    for (int f = 0; f < 4; ++f) O[f] = f32x4{0.f,0.f,0.f,0.f};

    u16* pb = sm + 49152 + wid * 640;        // [16][PB_STRIDE]
    #pragma unroll
    for (int t = 0; t < 8; ++t) {
        bf16x8 bv[4];
        #pragma unroll
        for (int f = 0; f < 4; ++f) {
            int d = f * 16 + r16;
            bv[f] = *(const bf16x8*)&Vt[d * 256 + ((((t * 32 + 8 * g) >> 3) ^ (d & 7)) << 3)];
        }
        #pragma unroll
        for (int tt = 0; tt < 2; ++tt) {
            int nf = 2 * t + tt;
            #pragma unroll
            for (int rr = 0; rr < 4; ++rr)
                pb[(4 * g + rr) * PB_STRIDE + tt * 16 + r16] = f2b(S[nf][rr]);
        }
        bf16x8 ap = *(const bf16x8*)&pb[r16 * PB_STRIDE + 8 * g];
        __builtin_amdgcn_s_setprio(1);
        #pragma unroll
        for (int f = 0; f < 4; ++f) O[f] = mfma(ap, bv[f], O[f]);
        __builtin_amdgcn_s_setprio(0);
    }

    #pragma unroll
    for (int f = 0; f < 4; ++f)
    #pragma unroll
    for (int rr = 0; rr < 4; ++rr)
        attn[(row0 + m0w + 4 * g + rr) * C_ + h * 64 + f * 16 + r16] = f2b(O[f][rr]);
}

// ---------------------------------------------------------------------------
// proj: attn(65536x384 bf16) @ w_proj(384x384) + bias -> f32 out.
// ---------------------------------------------------------------------------
__global__ __launch_bounds__(256, 2) void proj_kernel(
    const u16* __restrict__ attn, const u16* __restrict__ wPt,
    const float* __restrict__ bias, float* __restrict__ out)
{
    __shared__ alignas(16) u16 As[128*32];
    __shared__ alignas(16) u16 Bs[128*32];

    const int tid = threadIdx.x;
    const int lane = tid & 63, wid = tid >> 6;
    const int wr = wid >> 1, wc = wid & 1;
    const int g = lane >> 4, r16 = lane & 15;
    const int m0 = blockIdx.x * 128;
    const int n0 = blockIdx.y * 128;

    f32x4 acc[4][4];
    for (int i = 0; i < 4; i++) for (int j = 0; j < 4; j++) acc[i][j] = f32x4{0.f,0.f,0.f,0.f};

    for (int kt = 0; kt < C_; kt += 32) {
        for (int r = 0; r < 4; ++r) {
            int i = tid + 256*r;
            int mm = i >> 3;
            int kk = (i & 7) << 2;
            u16x4 v = *(const u16x4*)&attn[(size_t)(m0+mm)*C_ + kt + kk];
            int e = mm*32 + (((kk>>3) ^ ((mm>>1)&3))<<3) + (kk&7);
            *(u16x4*)&As[e] = v;
        }
        for (int r = 0; r < 4; ++r) {
            int i = tid + 256*r;
            int nn = i >> 3;
            int kk = (i & 7) << 2;
            u16x4 v = *(const u16x4*)&wPt[(size_t)(n0+nn)*C_ + kt + kk];
            int e = nn*32 + (((kk>>3) ^ ((nn>>1)&3))<<3) + (kk&7);
            *(u16x4*)&Bs[e] = v;
        }
        __syncthreads();

        bf16x8 a[4], b[4];
        for (int i = 0; i < 4; i++) {
            int row = wr*64 + i*16 + r16;
            a[i] = *(const bf16x8*)&As[row*32 + ((g ^ ((row>>1)&3))<<3)];
        }
        for (int j = 0; j < 4; j++) {
            int n = wc*64 + j*16 + r16;
            b[j] = *(const bf16x8*)&Bs[n*32 + ((g ^ ((n>>1)&3))<<3)];
        }
        for (int i = 0; i < 4; i++) for (int j = 0; j < 4; j++)
            acc[i][j] = mfma(a[i], b[j], acc[i][j]);
        __syncthreads();
    }

    for (int i = 0; i < 4; i++) for (int j = 0; j < 4; j++) for (int rr = 0; rr < 4; rr++) {
        size_t row = m0 + wr*64 + i*16 + g*4 + rr;
        int col = n0 + wc*64 + j*16 + r16;
        out[row*C_ + col] = acc[i][j][rr] + bias[col];
    }
}

// ---------------------------------------------------------------------------
extern "C" void kernel_launch(void* const* d_in, const int* in_sizes, int n_in,
                              void* d_out, int out_size, void* d_ws, size_t ws_size,
                              hipStream_t stream)
{
    const float* x      = (const float*)d_in[0];
    const float* w_qkv  = (const float*)d_in[1];
    const float* w_proj = (const float*)d_in[2];
    const float* b_proj = (const float*)d_in[3];
    float* out = (float*)d_out;

    u16* ws = (u16*)d_ws;
    u16* attnb = ws;                                  // 65536*384 u16 = 50 MB
    size_t off = (size_t)M_TOTAL * C_;
    u16* Wpk = ws + off; off += (size_t)H_ * KSTEPS * WKS_U16;
    u16* wPt = ws + off; off += (size_t)C_ * C_;

    hipFuncSetAttribute((const void*)fused_attn,
                        hipFuncAttributeMaxDynamicSharedMemorySize, FUSED_LDS);

    int prep_n = H_ * KSTEPS * 20 * 64 + C_ * C_;
    prep_w<<<dim3((prep_n + 255) / 256), 256, 0, stream>>>(w_qkv, w_proj, Wpk, wPt);
    fused_attn<<<dim3(NBLK), 1024, FUSED_LDS, stream>>>(x, Wpk, attnb);
    proj_kernel<<<dim3(M_TOTAL / 128, C_ / 128), 256, 0, stream>>>(attnb, wPt, b_proj, out);
}

// Round 9
// 243.828 us; speedup vs baseline: 1.2645x; 1.2357x over previous
//
#include <hip/hip_runtime.h>

typedef __bf16 bf16_t;
typedef __bf16 bf16x8 __attribute__((ext_vector_type(8)));
typedef float f32x4 __attribute__((ext_vector_type(4)));
typedef unsigned short u16;
typedef unsigned short u16x4 __attribute__((ext_vector_type(4)));
typedef unsigned int u32;

#define B_ 4
#define N_ 64
#define P_ 256
#define C_ 384
#define H_ 6
#define D_ 64
#define M_TOTAL 65536
#define NQKV 1152
#define KSTEPS 12                     // 384/32
#define NBLK (H_*B_*N_)               // 1536 = 8 XCDs * 192
#define WKS_U16 10240                 // 20KB per (h,ks): 12 hi frags + 8 lo frags x 1KB
#define WKS_BYTES 20480
// LDS map (u16 offsets):
//   stage bufs (phase 1): 3 x 10240 u16 at 0/10240/20480 (inside dead Kh/Kl region)
//   Kh 0..16384  Kl 16384..32768  Vt 32768..49152     (epilogue onward)
//   Qb = 49152 + wid*1024 (16 waves, 32KB)            (epilogue)
//   Pb = 49152 + wid*640  (20KB)                      (phase 3)
#define FUSED_LDS 131072
#define PB_STRIDE 40
#define SB() __builtin_amdgcn_sched_barrier(0)

#define GLOAD_LDS16(g, l) __builtin_amdgcn_global_load_lds( \
    (const __attribute__((address_space(1))) void*)(g), \
    (__attribute__((address_space(3))) void*)(l), 16, 0, 0)
#define GLOAD_LDS4(g, l) __builtin_amdgcn_global_load_lds( \
    (const __attribute__((address_space(1))) void*)(g), \
    (__attribute__((address_space(3))) void*)(l), 4, 0, 0)

__device__ __forceinline__ u16 f2b(float f){ return __builtin_bit_cast(u16, (bf16_t)f); }
__device__ __forceinline__ f32x4 mfma(bf16x8 a, bf16x8 b, f32x4 c){
    return __builtin_amdgcn_mfma_f32_16x16x32_bf16(a, b, c, 0, 0, 0);
}

// ---------------------------------------------------------------------------
// prep: (a) packed per-(h,ks) 20KB weight blocks [12 hi | 8 lo] fragments
//       (b) w_proj^T bf16
// ---------------------------------------------------------------------------
__global__ __launch_bounds__(256) void prep_w(
    const float* __restrict__ wqkv, const float* __restrict__ wproj,
    u16* __restrict__ Wpk, u16* __restrict__ wPt)
{
    int i = blockIdx.x * 256 + threadIdx.x;
    const int NSLOT = H_ * KSTEPS * 12 * 64;   // 55296
    if (i < NSLOT) {
        int lane = i & 63;
        int frag = i >> 6;
        int nf = frag % 12;
        int ks = (frag / 12) % KSTEPS;
        int h  = frag / (12 * KSTEPS);
        int part = nf >> 2;                        // 0=Q 1=K 2=V
        int nh   = (nf & 3) * 16 + (lane & 15);
        int col  = part * C_ + h * 64 + nh;
        int k0   = ks * 32 + (lane >> 4) * 8;
        size_t base = (size_t)(h * KSTEPS + ks) * WKS_U16;
        #pragma unroll
        for (int e = 0; e < 8; ++e) {
            float w = wqkv[(size_t)(k0 + e) * NQKV + col];
            bf16_t hi = (bf16_t)w;
            Wpk[base + nf * 512 + lane * 8 + e] = __builtin_bit_cast(u16, hi);
            if (nf < 8)
                Wpk[base + 6144 + nf * 512 + lane * 8 + e] = f2b(w - (float)hi);
        }
    }
    int j = i - NSLOT;
    if (j >= 0 && j < C_ * C_) {
        int k = j / C_, n = j % C_;
        wPt[(size_t)n * C_ + k] = f2b(wproj[j]);
    }
}

// ---------------------------------------------------------------------------
// fused per-(h, b*n) kernel: 1024 threads = 16 waves, wave owns 16 q-rows.
// Phase 1: 3-deep weight staging with COUNTED vmcnt + raw s_barrier -- each
// 20KB stage has two full k-steps of latency slack instead of <1 (the
// compiler's vmcnt(0)-before-__syncthreads was the per-ks stall).
// ---------------------------------------------------------------------------
__global__ __launch_bounds__(1024, 4) void fused_attn(
    const float* __restrict__ x, const u16* __restrict__ Wpk,
    u16* __restrict__ attn)
{
    extern __shared__ u16 sm[];
    u16* Kh = sm;              // valid from epilogue (stage bufs live here ph1)
    u16* Kl = sm + 16384;
    u16* Vt = sm + 32768;

    const int tid  = threadIdx.x;
    const int lane = tid & 63, wid = tid >> 6;
    const int g = lane >> 4, r16 = lane & 15;

    // XCD-chunk swizzle (bijective: 1536 = 8 * 192)
    const int p = blockIdx.x;
    const int logical = (p & 7) * (NBLK / 8) + (p >> 3);
    const int h  = logical % H_;
    const int bn = logical / H_;
    const size_t row0 = (size_t)bn * P_;
    const int m0w = wid * 16;

    // ---------------- phase 1: [Q|K|V](16 rows) = X @ W3head, split bf16 ---
    f32x4 acc[12];
    #pragma unroll
    for (int nf = 0; nf < 12; ++nf) acc[nf] = f32x4{0.f,0.f,0.f,0.f};

    const float* xr0 = x + (row0 + m0w + r16) * C_;
    const char* wbase = (const char*)Wpk + (size_t)h * (KSTEPS * WKS_BYTES);

    // uniform staging: every thread issues exactly one 16B + one 4B load
#define STAGE(ks_, b_) do { \
    const char* _gp = wbase + (size_t)(ks_) * WKS_BYTES; \
    char* _lp = (char*)(sm + (b_) * WKS_U16); \
    GLOAD_LDS16(_gp + tid * 16, _lp + tid * 16); \
    GLOAD_LDS4(_gp + 16384 + tid * 4, _lp + 16384 + tid * 4); \
} while (0)

    f32x4 xr[2][2];
#define XLOAD(ks_, par_) do { \
    const float* _xp = xr0 + (ks_) * 32 + 8 * g; \
    xr[par_][0] = *(const f32x4*)_xp; xr[par_][1] = *(const f32x4*)(_xp + 4); \
} while (0)

    bf16x8 ah, al;
#define SPLIT_A(par_) do { \
    _Pragma("unroll") \
    for (int e = 0; e < 4; ++e) { \
        bf16_t h0 = (bf16_t)xr[par_][0][e], h1 = (bf16_t)xr[par_][1][e]; \
        ah[e]   = h0; al[e]   = (bf16_t)(xr[par_][0][e] - (float)h0); \
        ah[4+e] = h1; al[4+e] = (bf16_t)(xr[par_][1][e] - (float)h1); \
    } } while (0)

    // prologue: stage ks=0,1; x(0). vmcnt(2) leaves only stage(1) in flight.
    STAGE(0, 0);
    XLOAD(0, 0);
    STAGE(1, 1);
    SB();
    asm volatile("s_waitcnt vmcnt(2)" ::: "memory");
    __builtin_amdgcn_s_barrier();
    SB();

    #pragma unroll
    for (int ks = 0; ks < KSTEPS; ++ks) {
        const int par = ks & 1, nxt = par ^ 1;
        if (ks + 2 < KSTEPS) STAGE(ks + 2, (ks + 2) % 3);   // 2 loads
        if (ks + 1 < KSTEPS) XLOAD(ks + 1, nxt);            // 2 loads
        SPLIT_A(par);

        const u16* stg = sm + (ks % 3) * WKS_U16;
        #pragma unroll
        for (int nf = 0; nf < 8; ++nf) {    // Q,K: split 3x
            bf16x8 bh = *(const bf16x8*)&stg[nf * 512 + lane * 8];
            bf16x8 bl = *(const bf16x8*)&stg[6144 + nf * 512 + lane * 8];
            acc[nf] = mfma(ah, bh, acc[nf]);
            acc[nf] = mfma(ah, bl, acc[nf]);
            acc[nf] = mfma(al, bh, acc[nf]);
        }
        #pragma unroll
        for (int nf = 8; nf < 12; ++nf) {   // V: plain
            bf16x8 bh = *(const bf16x8*)&stg[nf * 512 + lane * 8];
            acc[nf] = mfma(ah, bh, acc[nf]);
        }

        if (ks < KSTEPS - 1) {
            // counted drain: allow stage(ks+2) + x(ks+1) (4 youngest) to fly;
            // forces stage(ks+1) complete. Tail ks=10: only x(11) in flight.
            SB();
            if (ks + 2 < KSTEPS) asm volatile("s_waitcnt vmcnt(4)" ::: "memory");
            else                 asm volatile("s_waitcnt vmcnt(2)" ::: "memory");
            __builtin_amdgcn_s_barrier();
            SB();
        } else {
            __syncthreads();   // full drain: stage region reused as Kh/Kl next
        }
    }

    // ---- epilogue: K -> Kh/Kl (split), V -> Vt (b64-packed), swizzled ----
    #pragma unroll
    for (int f = 0; f < 4; ++f) {
        const int d = f * 16 + r16;
        const int q0 = m0w + 4 * g;
        u16x4 vv;
        #pragma unroll
        for (int rr = 0; rr < 4; ++rr) vv[rr] = f2b(acc[8 + f][rr]);
        *(u16x4*)&Vt[d * 256 + (((q0 >> 3) ^ (d & 7)) << 3) + (q0 & 7)] = vv;
        #pragma unroll
        for (int rr = 0; rr < 4; ++rr) {
            int q = q0 + rr;
            int ek = q * 64 + (((d >> 3) ^ (q & 7)) << 3) + (d & 7);
            float kv = acc[4 + f][rr];
            bf16_t khi = (bf16_t)kv;
            Kh[ek] = __builtin_bit_cast(u16, khi);
            Kl[ek] = f2b(kv - (float)khi);
        }
    }

    // ---- Q bounce (per-wave region, two passes hi/lo) ----
    u16* myQb = sm + 49152 + wid * 1024;   // [16][64] swizzled
    bf16x8 aqh[2], aql[2];
    #pragma unroll
    for (int f = 0; f < 4; ++f)
    #pragma unroll
    for (int rr = 0; rr < 4; ++rr) {
        int r = 4 * g + rr;
        int c = f * 16 + r16;
        myQb[r * 64 + (((c >> 3) ^ (r & 7)) << 3) + (c & 7)] = f2b(acc[f][rr]);
    }
    #pragma unroll
    for (int k2 = 0; k2 < 2; ++k2)
        aqh[k2] = *(const bf16x8*)&myQb[r16 * 64 + (((k2 * 4 + g) ^ (r16 & 7)) << 3)];
    SB();   // keep lo-pass writes after hi-pass reads
    #pragma unroll
    for (int f = 0; f < 4; ++f)
    #pragma unroll
    for (int rr = 0; rr < 4; ++rr) {
        int r = 4 * g + rr;
        int c = f * 16 + r16;
        float v = acc[f][rr];
        bf16_t hi = (bf16_t)v;
        myQb[r * 64 + (((c >> 3) ^ (r & 7)) << 3) + (c & 7)] = f2b(v - (float)hi);
    }
    #pragma unroll
    for (int k2 = 0; k2 < 2; ++k2)
        aql[k2] = *(const bf16x8*)&myQb[r16 * 64 + (((k2 * 4 + g) ^ (r16 & 7)) << 3)];

    __syncthreads();   // Kh/Kl/Vt visible block-wide

    // ---------------- phase 2: S = Q K^T (split, 3 MFMA), prefetch 1 nf ----
    f32x4 S[16];
    #pragma unroll
    for (int nf = 0; nf < 16; ++nf) S[nf] = f32x4{0.f,0.f,0.f,0.f};

    // loop-invariant bases: e(nf,k2) = nf*1024 + kb[k2]
    const int kb0 = r16 * 64 + (((0 * 4 + g) ^ (r16 & 7)) << 3);
    const int kb1 = r16 * 64 + (((1 * 4 + g) ^ (r16 & 7)) << 3);

    bf16x8 khv[2][2], klv[2][2];
    {
        khv[0][0] = *(const bf16x8*)&Kh[kb0];
        klv[0][0] = *(const bf16x8*)&Kl[kb0];
        khv[0][1] = *(const bf16x8*)&Kh[kb1];
        klv[0][1] = *(const bf16x8*)&Kl[kb1];
    }
    #pragma unroll
    for (int nf = 0; nf < 16; ++nf) {
        const int par = nf & 1, nxt = par ^ 1;
        if (nf < 15) {
            const int o = (nf + 1) * 1024;
            khv[nxt][0] = *(const bf16x8*)&Kh[o + kb0];
            klv[nxt][0] = *(const bf16x8*)&Kl[o + kb0];
            khv[nxt][1] = *(const bf16x8*)&Kh[o + kb1];
            klv[nxt][1] = *(const bf16x8*)&Kl[o + kb1];
        }
        SB();
        __builtin_amdgcn_s_setprio(1);
        #pragma unroll
        for (int k2 = 0; k2 < 2; ++k2) {
            S[nf] = mfma(aqh[k2], khv[par][k2], S[nf]);
            S[nf] = mfma(aqh[k2], klv[par][k2], S[nf]);
            S[nf] = mfma(aql[k2], khv[par][k2], S[nf]);
        }
        __builtin_amdgcn_s_setprio(0);
        SB();
    }

    // ---------------- softmax (rows lane-spread over 16 lanes) -------------
    {
        float mrow[4] = {-1e30f,-1e30f,-1e30f,-1e30f};
        #pragma unroll
        for (int nf = 0; nf < 16; ++nf)
            #pragma unroll
            for (int rr = 0; rr < 4; ++rr) mrow[rr] = fmaxf(mrow[rr], S[nf][rr]);
        #pragma unroll
        for (int mask = 1; mask < 16; mask <<= 1)
            #pragma unroll
            for (int rr = 0; rr < 4; ++rr) mrow[rr] = fmaxf(mrow[rr], __shfl_xor(mrow[rr], mask, 64));
        float ssum[4] = {0.f,0.f,0.f,0.f};
        #pragma unroll
        for (int nf = 0; nf < 16; ++nf)
            #pragma unroll
            for (int rr = 0; rr < 4; ++rr) {
                float pv = __expf((S[nf][rr] - mrow[rr]) * 64.0f);  // scale = D
                S[nf][rr] = pv;
                ssum[rr] += pv;
            }
        #pragma unroll
        for (int mask = 1; mask < 16; mask <<= 1)
            #pragma unroll
            for (int rr = 0; rr < 4; ++rr) ssum[rr] += __shfl_xor(ssum[rr], mask, 64);
        float inv_[4];
        #pragma unroll
        for (int rr = 0; rr < 4; ++rr) inv_[rr] = 1.0f / ssum[rr];
        #pragma unroll
        for (int nf = 0; nf < 16; ++nf)       // fold 1/sum into P now
            #pragma unroll
            for (int rr = 0; rr < 4; ++rr) S[nf][rr] *= inv_[rr];
    }

    // ---------------- phase 3: O = P V (per-wave bounce, stride 40) --------
    f32x4 O[4];
    #pragma unroll
    for (int f = 0; f < 4; ++f) O[f] = f32x4{0.f,0.f,0.f,0.f};

    u16* pb = sm + 49152 + wid * 640;        // [16][PB_STRIDE]
    const int vc = r16 & 7;                  // loop-invariant XOR operand
    #pragma unroll
    for (int t = 0; t < 8; ++t) {
        bf16x8 bv[4];
        const int vo = (((4 * t + g) ^ vc) << 3) + r16 * 256;
        #pragma unroll
        for (int f = 0; f < 4; ++f)
            bv[f] = *(const bf16x8*)&Vt[f * 4096 + vo];
        #pragma unroll
        for (int tt = 0; tt < 2; ++tt) {
            int nf = 2 * t + tt;
            #pragma unroll
            for (int rr = 0; rr < 4; ++rr)
                pb[(4 * g + rr) * PB_STRIDE + tt * 16 + r16] = f2b(S[nf][rr]);
        }
        bf16x8 ap = *(const bf16x8*)&pb[r16 * PB_STRIDE + 8 * g];
        __builtin_amdgcn_s_setprio(1);
        #pragma unroll
        for (int f = 0; f < 4; ++f) O[f] = mfma(ap, bv[f], O[f]);
        __builtin_amdgcn_s_setprio(0);
    }

    #pragma unroll
    for (int f = 0; f < 4; ++f)
    #pragma unroll
    for (int rr = 0; rr < 4; ++rr)
        attn[(row0 + m0w + 4 * g + rr) * C_ + h * 64 + f * 16 + r16] = f2b(O[f][rr]);
}

// ---------------------------------------------------------------------------
// proj: attn(65536x384 bf16) @ w_proj(384x384) + bias -> f32 out.
// ---------------------------------------------------------------------------
__global__ __launch_bounds__(256, 2) void proj_kernel(
    const u16* __restrict__ attn, const u16* __restrict__ wPt,
    const float* __restrict__ bias, float* __restrict__ out)
{
    __shared__ alignas(16) u16 As[128*32];
    __shared__ alignas(16) u16 Bs[128*32];

    const int tid = threadIdx.x;
    const int lane = tid & 63, wid = tid >> 6;
    const int wr = wid >> 1, wc = wid & 1;
    const int g = lane >> 4, r16 = lane & 15;
    const int m0 = blockIdx.x * 128;
    const int n0 = blockIdx.y * 128;

    f32x4 acc[4][4];
    for (int i = 0; i < 4; i++) for (int j = 0; j < 4; j++) acc[i][j] = f32x4{0.f,0.f,0.f,0.f};

    for (int kt = 0; kt < C_; kt += 32) {
        for (int r = 0; r < 4; ++r) {
            int i = tid + 256*r;
            int mm = i >> 3;
            int kk = (i & 7) << 2;
            u16x4 v = *(const u16x4*)&attn[(size_t)(m0+mm)*C_ + kt + kk];
            int e = mm*32 + (((kk>>3) ^ ((mm>>1)&3))<<3) + (kk&7);
            *(u16x4*)&As[e] = v;
        }
        for (int r = 0; r < 4; ++r) {
            int i = tid + 256*r;
            int nn = i >> 3;
            int kk = (i & 7) << 2;
            u16x4 v = *(const u16x4*)&wPt[(size_t)(n0+nn)*C_ + kt + kk];
            int e = nn*32 + (((kk>>3) ^ ((nn>>1)&3))<<3) + (kk&7);
            *(u16x4*)&Bs[e] = v;
        }
        __syncthreads();

        bf16x8 a[4], b[4];
        for (int i = 0; i < 4; i++) {
            int row = wr*64 + i*16 + r16;
            a[i] = *(const bf16x8*)&As[row*32 + ((g ^ ((row>>1)&3))<<3)];
        }
        for (int j = 0; j < 4; j++) {
            int n = wc*64 + j*16 + r16;
            b[j] = *(const bf16x8*)&Bs[n*32 + ((g ^ ((n>>1)&3))<<3)];
        }
        for (int i = 0; i < 4; i++) for (int j = 0; j < 4; j++)
            acc[i][j] = mfma(a[i], b[j], acc[i][j]);
        __syncthreads();
    }

    for (int i = 0; i < 4; i++) for (int j = 0; j < 4; j++) for (int rr = 0; rr < 4; rr++) {
        size_t row = m0 + wr*64 + i*16 + g*4 + rr;
        int col = n0 + wc*64 + j*16 + r16;
        out[row*C_ + col] = acc[i][j][rr] + bias[col];
    }
}

// ---------------------------------------------------------------------------
extern "C" void kernel_launch(void* const* d_in, const int* in_sizes, int n_in,
                              void* d_out, int out_size, void* d_ws, size_t ws_size,
                              hipStream_t stream)
{
    const float* x      = (const float*)d_in[0];
    const float* w_qkv  = (const float*)d_in[1];
    const float* w_proj = (const float*)d_in[2];
    const float* b_proj = (const float*)d_in[3];
    float* out = (float*)d_out;

    u16* ws = (u16*)d_ws;
    u16* attnb = ws;                                  // 65536*384 u16 = 50 MB
    size_t off = (size_t)M_TOTAL * C_;
    u16* Wpk = ws + off; off += (size_t)H_ * KSTEPS * WKS_U16;
    u16* wPt = ws + off; off += (size_t)C_ * C_;

    hipFuncSetAttribute((const void*)fused_attn,
                        hipFuncAttributeMaxDynamicSharedMemorySize, FUSED_LDS);

    int prep_n = H_ * KSTEPS * 12 * 64 + C_ * C_;
    prep_w<<<dim3((prep_n + 255) / 256), 256, 0, stream>>>(w_qkv, w_proj, Wpk, wPt);
    fused_attn<<<dim3(NBLK), 1024, FUSED_LDS, stream>>>(x, Wpk, attnb);
    proj_kernel<<<dim3(M_TOTAL / 128, C_ / 128), 256, 0, stream>>>(attnb, wPt, b_proj, out);
}

// Round 10
// 235.953 us; speedup vs baseline: 1.3067x; 1.0334x over previous
//
#include <hip/hip_runtime.h>

typedef __bf16 bf16_t;
typedef __bf16 bf16x8 __attribute__((ext_vector_type(8)));
typedef float f32x4 __attribute__((ext_vector_type(4)));
typedef unsigned short u16;
typedef unsigned short u16x4 __attribute__((ext_vector_type(4)));
typedef unsigned int u32;

#define B_ 4
#define N_ 64
#define P_ 256
#define C_ 384
#define H_ 6
#define D_ 64
#define M_TOTAL 65536
#define NQKV 1152
#define KSTEPS 12                     // 384/32
#define NBLK (H_*B_*N_)               // 1536 = 8 XCDs * 192
#define WKS_U16 10240                 // 20KB per (h,ks): 12 hi frags + 8 lo frags x 1KB
#define WKS_BYTES 20480
// LDS map (u16 offsets):
//   stage bufs (phase 1): 3 x 10240 u16 at 0/10240/20480 (inside dead Kh/Kl region)
//   Kh 0..16384  Kl 16384..32768  Vt 32768..49152     (epilogue onward)
//   per-wave region: 49152 + wid*1024 (16 waves x 2KB)
//     = Q bounce [16][64] (epilogue), then P tile [16][40] (phase 3)
#define FUSED_LDS 131072
#define PB_STRIDE 40
#define SB() __builtin_amdgcn_sched_barrier(0)

#define GLOAD_LDS16(g, l) __builtin_amdgcn_global_load_lds( \
    (const __attribute__((address_space(1))) void*)(g), \
    (__attribute__((address_space(3))) void*)(l), 16, 0, 0)
#define GLOAD_LDS4(g, l) __builtin_amdgcn_global_load_lds( \
    (const __attribute__((address_space(1))) void*)(g), \
    (__attribute__((address_space(3))) void*)(l), 4, 0, 0)

__device__ __forceinline__ u16 f2b(float f){ return __builtin_bit_cast(u16, (bf16_t)f); }
__device__ __forceinline__ f32x4 mfma(bf16x8 a, bf16x8 b, f32x4 c){
    return __builtin_amdgcn_mfma_f32_16x16x32_bf16(a, b, c, 0, 0, 0);
}

// ---------------------------------------------------------------------------
// prep: (a) packed per-(h,ks) 20KB weight blocks [12 hi | 8 lo] fragments
//       (b) w_proj^T bf16
// ---------------------------------------------------------------------------
__global__ __launch_bounds__(256) void prep_w(
    const float* __restrict__ wqkv, const float* __restrict__ wproj,
    u16* __restrict__ Wpk, u16* __restrict__ wPt)
{
    int i = blockIdx.x * 256 + threadIdx.x;
    const int NSLOT = H_ * KSTEPS * 12 * 64;   // 55296
    if (i < NSLOT) {
        int lane = i & 63;
        int frag = i >> 6;
        int nf = frag % 12;
        int ks = (frag / 12) % KSTEPS;
        int h  = frag / (12 * KSTEPS);
        int part = nf >> 2;                        // 0=Q 1=K 2=V
        int nh   = (nf & 3) * 16 + (lane & 15);
        int col  = part * C_ + h * 64 + nh;
        int k0   = ks * 32 + (lane >> 4) * 8;
        size_t base = (size_t)(h * KSTEPS + ks) * WKS_U16;
        #pragma unroll
        for (int e = 0; e < 8; ++e) {
            float w = wqkv[(size_t)(k0 + e) * NQKV + col];
            bf16_t hi = (bf16_t)w;
            Wpk[base + nf * 512 + lane * 8 + e] = __builtin_bit_cast(u16, hi);
            if (nf < 8)
                Wpk[base + 6144 + nf * 512 + lane * 8 + e] = f2b(w - (float)hi);
        }
    }
    int j = i - NSLOT;
    if (j >= 0 && j < C_ * C_) {
        int k = j / C_, n = j % C_;
        wPt[(size_t)n * C_ + k] = f2b(wproj[j]);
    }
}

// ---------------------------------------------------------------------------
// fused per-(h, b*n) kernel: 1024 threads = 16 waves, wave owns 16 q-rows.
// Phase 1: 3-deep weight staging with counted vmcnt + raw s_barrier (r9).
// Phase 2: SWAPPED QK^T (A=K, B=Q) -> S^T layout: each lane holds one q-row's
//   64 score samples; softmax = in-lane reduce + 2 shuffles; P-bounce becomes
//   2 packed b64 writes + 1 b128 read per PV tile (was 8 scalar writes).
// ---------------------------------------------------------------------------
__global__ __launch_bounds__(1024, 4) void fused_attn(
    const float* __restrict__ x, const u16* __restrict__ Wpk,
    u16* __restrict__ attn)
{
    extern __shared__ u16 sm[];
    u16* Kh = sm;              // valid from epilogue (stage bufs live here ph1)
    u16* Kl = sm + 16384;
    u16* Vt = sm + 32768;

    const int tid  = threadIdx.x;
    const int lane = tid & 63, wid = tid >> 6;
    const int g = lane >> 4, r16 = lane & 15;

    // XCD-chunk swizzle (bijective: 1536 = 8 * 192)
    const int p = blockIdx.x;
    const int logical = (p & 7) * (NBLK / 8) + (p >> 3);
    const int h  = logical % H_;
    const int bn = logical / H_;
    const size_t row0 = (size_t)bn * P_;
    const int m0w = wid * 16;

    // ---------------- phase 1: [Q|K|V](16 rows) = X @ W3head, split bf16 ---
    f32x4 acc[12];
    #pragma unroll
    for (int nf = 0; nf < 12; ++nf) acc[nf] = f32x4{0.f,0.f,0.f,0.f};

    const float* xr0 = x + (row0 + m0w + r16) * C_;
    const char* wbase = (const char*)Wpk + (size_t)h * (KSTEPS * WKS_BYTES);

    // uniform staging: every thread issues exactly one 16B + one 4B load
#define STAGE(ks_, b_) do { \
    const char* _gp = wbase + (size_t)(ks_) * WKS_BYTES; \
    char* _lp = (char*)(sm + (b_) * WKS_U16); \
    GLOAD_LDS16(_gp + tid * 16, _lp + tid * 16); \
    GLOAD_LDS4(_gp + 16384 + tid * 4, _lp + 16384 + tid * 4); \
} while (0)

    f32x4 xr[2][2];
#define XLOAD(ks_, par_) do { \
    const float* _xp = xr0 + (ks_) * 32 + 8 * g; \
    xr[par_][0] = *(const f32x4*)_xp; xr[par_][1] = *(const f32x4*)(_xp + 4); \
} while (0)

    bf16x8 ah, al;
#define SPLIT_A(par_) do { \
    _Pragma("unroll") \
    for (int e = 0; e < 4; ++e) { \
        bf16_t h0 = (bf16_t)xr[par_][0][e], h1 = (bf16_t)xr[par_][1][e]; \
        ah[e]   = h0; al[e]   = (bf16_t)(xr[par_][0][e] - (float)h0); \
        ah[4+e] = h1; al[4+e] = (bf16_t)(xr[par_][1][e] - (float)h1); \
    } } while (0)

    // prologue: stage ks=0,1; x(0). vmcnt(2) leaves only stage(1) in flight.
    STAGE(0, 0);
    XLOAD(0, 0);
    STAGE(1, 1);
    SB();
    asm volatile("s_waitcnt vmcnt(2)" ::: "memory");
    __builtin_amdgcn_s_barrier();
    SB();

    #pragma unroll
    for (int ks = 0; ks < KSTEPS; ++ks) {
        const int par = ks & 1, nxt = par ^ 1;
        if (ks + 2 < KSTEPS) STAGE(ks + 2, (ks + 2) % 3);   // 2 loads
        if (ks + 1 < KSTEPS) XLOAD(ks + 1, nxt);            // 2 loads
        SPLIT_A(par);

        const u16* stg = sm + (ks % 3) * WKS_U16;
        #pragma unroll
        for (int nf = 0; nf < 8; ++nf) {    // Q,K: split 3x
            bf16x8 bh = *(const bf16x8*)&stg[nf * 512 + lane * 8];
            bf16x8 bl = *(const bf16x8*)&stg[6144 + nf * 512 + lane * 8];
            acc[nf] = mfma(ah, bh, acc[nf]);
            acc[nf] = mfma(ah, bl, acc[nf]);
            acc[nf] = mfma(al, bh, acc[nf]);
        }
        #pragma unroll
        for (int nf = 8; nf < 12; ++nf) {   // V: plain
            bf16x8 bh = *(const bf16x8*)&stg[nf * 512 + lane * 8];
            acc[nf] = mfma(ah, bh, acc[nf]);
        }

        if (ks < KSTEPS - 1) {
            // counted drain: allow stage(ks+2) + x(ks+1) (4 youngest) to fly;
            // forces stage(ks+1) complete. Tail ks=10: only x(11) in flight.
            SB();
            if (ks + 2 < KSTEPS) asm volatile("s_waitcnt vmcnt(4)" ::: "memory");
            else                 asm volatile("s_waitcnt vmcnt(2)" ::: "memory");
            __builtin_amdgcn_s_barrier();
            SB();
        } else {
            __syncthreads();   // full drain: stage region reused as Kh/Kl next
        }
    }

    // ---- epilogue: K -> Kh/Kl (split), V -> Vt (b64-packed), swizzled ----
    #pragma unroll
    for (int f = 0; f < 4; ++f) {
        const int d = f * 16 + r16;
        const int q0 = m0w + 4 * g;
        u16x4 vv;
        #pragma unroll
        for (int rr = 0; rr < 4; ++rr) vv[rr] = f2b(acc[8 + f][rr]);
        *(u16x4*)&Vt[d * 256 + (((q0 >> 3) ^ (d & 7)) << 3) + (q0 & 7)] = vv;
        #pragma unroll
        for (int rr = 0; rr < 4; ++rr) {
            int q = q0 + rr;
            int ek = q * 64 + (((d >> 3) ^ (q & 7)) << 3) + (d & 7);
            float kv = acc[4 + f][rr];
            bf16_t khi = (bf16_t)kv;
            Kh[ek] = __builtin_bit_cast(u16, khi);
            Kl[ek] = f2b(kv - (float)khi);
        }
    }

    // ---- Q bounce (per-wave region, two passes hi/lo) ----
    u16* myQb = sm + 49152 + wid * 1024;   // [16][64] swizzled
    bf16x8 aqh[2], aql[2];
    #pragma unroll
    for (int f = 0; f < 4; ++f)
    #pragma unroll
    for (int rr = 0; rr < 4; ++rr) {
        int r = 4 * g + rr;
        int c = f * 16 + r16;
        myQb[r * 64 + (((c >> 3) ^ (r & 7)) << 3) + (c & 7)] = f2b(acc[f][rr]);
    }
    #pragma unroll
    for (int k2 = 0; k2 < 2; ++k2)
        aqh[k2] = *(const bf16x8*)&myQb[r16 * 64 + (((k2 * 4 + g) ^ (r16 & 7)) << 3)];
    SB();   // keep lo-pass writes after hi-pass reads
    #pragma unroll
    for (int f = 0; f < 4; ++f)
    #pragma unroll
    for (int rr = 0; rr < 4; ++rr) {
        int r = 4 * g + rr;
        int c = f * 16 + r16;
        float v = acc[f][rr];
        bf16_t hi = (bf16_t)v;
        myQb[r * 64 + (((c >> 3) ^ (r & 7)) << 3) + (c & 7)] = f2b(v - (float)hi);
    }
    #pragma unroll
    for (int k2 = 0; k2 < 2; ++k2)
        aql[k2] = *(const bf16x8*)&myQb[r16 * 64 + (((k2 * 4 + g) ^ (r16 & 7)) << 3)];

    __syncthreads();   // Kh/Kl/Vt visible block-wide

    // ---------------- phase 2: S^T = K Q^T (swapped operands, split 3x) ----
    // C-layout: lane (g,r16), reg rr holds S[q = m0w+r16][key = 16nf+4g+rr].
    f32x4 S[16];
    #pragma unroll
    for (int nf = 0; nf < 16; ++nf) S[nf] = f32x4{0.f,0.f,0.f,0.f};

    const int kb0 = r16 * 64 + (((0 * 4 + g) ^ (r16 & 7)) << 3);
    const int kb1 = r16 * 64 + (((1 * 4 + g) ^ (r16 & 7)) << 3);

    bf16x8 khv[2][2], klv[2][2];
    {
        khv[0][0] = *(const bf16x8*)&Kh[kb0];
        klv[0][0] = *(const bf16x8*)&Kl[kb0];
        khv[0][1] = *(const bf16x8*)&Kh[kb1];
        klv[0][1] = *(const bf16x8*)&Kl[kb1];
    }
    #pragma unroll
    for (int nf = 0; nf < 16; ++nf) {
        const int par = nf & 1, nxt = par ^ 1;
        if (nf < 15) {
            const int o = (nf + 1) * 1024;
            khv[nxt][0] = *(const bf16x8*)&Kh[o + kb0];
            klv[nxt][0] = *(const bf16x8*)&Kl[o + kb0];
            khv[nxt][1] = *(const bf16x8*)&Kh[o + kb1];
            klv[nxt][1] = *(const bf16x8*)&Kl[o + kb1];
        }
        SB();
        __builtin_amdgcn_s_setprio(1);
        #pragma unroll
        for (int k2 = 0; k2 < 2; ++k2) {
            S[nf] = mfma(khv[par][k2], aqh[k2], S[nf]);   // kh*qh
            S[nf] = mfma(klv[par][k2], aqh[k2], S[nf]);   // kl*qh
            S[nf] = mfma(khv[par][k2], aql[k2], S[nf]);   // kh*ql
        }
        __builtin_amdgcn_s_setprio(0);
        SB();
    }

    // ---------------- softmax: each lane owns one q-row's 64 samples -------
    float inv_;
    {
        float m = -1e30f;
        #pragma unroll
        for (int nf = 0; nf < 16; ++nf)
            #pragma unroll
            for (int rr = 0; rr < 4; ++rr) m = fmaxf(m, S[nf][rr]);
        m = fmaxf(m, __shfl_xor(m, 16, 64));
        m = fmaxf(m, __shfl_xor(m, 32, 64));
        float s = 0.f;
        #pragma unroll
        for (int nf = 0; nf < 16; ++nf)
            #pragma unroll
            for (int rr = 0; rr < 4; ++rr) {
                float pv = __expf((S[nf][rr] - m) * 64.0f);  // scale = D
                S[nf][rr] = pv;
                s += pv;
            }
        s += __shfl_xor(s, 16, 64);
        s += __shfl_xor(s, 32, 64);
        inv_ = 1.0f / s;
    }

    // ---------------- phase 3: O = P V (packed b64 P-bounce) ---------------
    // Per tile t: lane (g,r16) writes its kappa-quads (nu=0,1) as 2 x b64 at
    // [r16][16*nu + 4g]; reads A-frag b128 at [r16][8g]. Same-wave DS order
    // makes the single buffer race-free.
    f32x4 O[4];
    #pragma unroll
    for (int f = 0; f < 4; ++f) O[f] = f32x4{0.f,0.f,0.f,0.f};

    u16* pt = sm + 49152 + wid * 1024;       // reuse Q-bounce region: [16][40]
    const int vc = r16 & 7;
    #pragma unroll
    for (int t = 0; t < 8; ++t) {
        bf16x8 bv[4];
        const int vo = (((4 * t + g) ^ vc) << 3) + r16 * 256;
        #pragma unroll
        for (int f = 0; f < 4; ++f)
            bv[f] = *(const bf16x8*)&Vt[f * 4096 + vo];
        #pragma unroll
        for (int nu = 0; nu < 2; ++nu) {
            int nf = 2 * t + nu;
            u16x4 pk;
            #pragma unroll
            for (int rr = 0; rr < 4; ++rr) pk[rr] = f2b(S[nf][rr] * inv_);
            *(u16x4*)&pt[r16 * PB_STRIDE + nu * 16 + 4 * g] = pk;
        }
        bf16x8 ap = *(const bf16x8*)&pt[r16 * PB_STRIDE + 8 * g];
        __builtin_amdgcn_s_setprio(1);
        #pragma unroll
        for (int f = 0; f < 4; ++f) O[f] = mfma(ap, bv[f], O[f]);
        __builtin_amdgcn_s_setprio(0);
    }

    #pragma unroll
    for (int f = 0; f < 4; ++f)
    #pragma unroll
    for (int rr = 0; rr < 4; ++rr)
        attn[(row0 + m0w + 4 * g + rr) * C_ + h * 64 + f * 16 + r16] = f2b(O[f][rr]);
}

// ---------------------------------------------------------------------------
// proj: attn(65536x384 bf16) @ w_proj(384x384) + bias -> f32 out.
// ---------------------------------------------------------------------------
__global__ __launch_bounds__(256, 2) void proj_kernel(
    const u16* __restrict__ attn, const u16* __restrict__ wPt,
    const float* __restrict__ bias, float* __restrict__ out)
{
    __shared__ alignas(16) u16 As[128*32];
    __shared__ alignas(16) u16 Bs[128*32];

    const int tid = threadIdx.x;
    const int lane = tid & 63, wid = tid >> 6;
    const int wr = wid >> 1, wc = wid & 1;
    const int g = lane >> 4, r16 = lane & 15;
    const int m0 = blockIdx.x * 128;
    const int n0 = blockIdx.y * 128;

    f32x4 acc[4][4];
    for (int i = 0; i < 4; i++) for (int j = 0; j < 4; j++) acc[i][j] = f32x4{0.f,0.f,0.f,0.f};

    for (int kt = 0; kt < C_; kt += 32) {
        for (int r = 0; r < 4; ++r) {
            int i = tid + 256*r;
            int mm = i >> 3;
            int kk = (i & 7) << 2;
            u16x4 v = *(const u16x4*)&attn[(size_t)(m0+mm)*C_ + kt + kk];
            int e = mm*32 + (((kk>>3) ^ ((mm>>1)&3))<<3) + (kk&7);
            *(u16x4*)&As[e] = v;
        }
        for (int r = 0; r < 4; ++r) {
            int i = tid + 256*r;
            int nn = i >> 3;
            int kk = (i & 7) << 2;
            u16x4 v = *(const u16x4*)&wPt[(size_t)(n0+nn)*C_ + kt + kk];
            int e = nn*32 + (((kk>>3) ^ ((nn>>1)&3))<<3) + (kk&7);
            *(u16x4*)&Bs[e] = v;
        }
        __syncthreads();

        bf16x8 a[4], b[4];
        for (int i = 0; i < 4; i++) {
            int row = wr*64 + i*16 + r16;
            a[i] = *(const bf16x8*)&As[row*32 + ((g ^ ((row>>1)&3))<<3)];
        }
        for (int j = 0; j < 4; j++) {
            int n = wc*64 + j*16 + r16;
            b[j] = *(const bf16x8*)&Bs[n*32 + ((g ^ ((n>>1)&3))<<3)];
        }
        for (int i = 0; i < 4; i++) for (int j = 0; j < 4; j++)
            acc[i][j] = mfma(a[i], b[j], acc[i][j]);
        __syncthreads();
    }

    for (int i = 0; i < 4; i++) for (int j = 0; j < 4; j++) for (int rr = 0; rr < 4; rr++) {
        size_t row = m0 + wr*64 + i*16 + g*4 + rr;
        int col = n0 + wc*64 + j*16 + r16;
        out[row*C_ + col] = acc[i][j][rr] + bias[col];
    }
}

// ---------------------------------------------------------------------------
extern "C" void kernel_launch(void* const* d_in, const int* in_sizes, int n_in,
                              void* d_out, int out_size, void* d_ws, size_t ws_size,
                              hipStream_t stream)
{
    const float* x      = (const float*)d_in[0];
    const float* w_qkv  = (const float*)d_in[1];
    const float* w_proj = (const float*)d_in[2];
    const float* b_proj = (const float*)d_in[3];
    float* out = (float*)d_out;

    u16* ws = (u16*)d_ws;
    u16* attnb = ws;                                  // 65536*384 u16 = 50 MB
    size_t off = (size_t)M_TOTAL * C_;
    u16* Wpk = ws + off; off += (size_t)H_ * KSTEPS * WKS_U16;
    u16* wPt = ws + off; off += (size_t)C_ * C_;

    hipFuncSetAttribute((const void*)fused_attn,
                        hipFuncAttributeMaxDynamicSharedMemorySize, FUSED_LDS);

    int prep_n = H_ * KSTEPS * 12 * 64 + C_ * C_;
    prep_w<<<dim3((prep_n + 255) / 256), 256, 0, stream>>>(w_qkv, w_proj, Wpk, wPt);
    fused_attn<<<dim3(NBLK), 1024, FUSED_LDS, stream>>>(x, Wpk, attnb);
    proj_kernel<<<dim3(M_TOTAL / 128, C_ / 128), 256, 0, stream>>>(attnb, wPt, b_proj, out);
}